// Round 1
// baseline (337.225 us; speedup 1.0000x reference)
//
#include <hip/hip_runtime.h>

// Range-aware attention, bf16 MFMA pipeline.
// B=2, S=2048, D=1024, H=16, dk=64. EPS=0.1.

typedef __bf16 bf16x8 __attribute__((ext_vector_type(8)));
typedef float f32x4 __attribute__((ext_vector_type(4)));

#define EPSG 0.1f

__device__ __forceinline__ unsigned short f2bf(float f) {
  unsigned int u = __float_as_uint(f);
  u += 0x7FFFu + ((u >> 16) & 1u);   // RNE
  return (unsigned short)(u >> 16);
}

__device__ __forceinline__ void gload_lds16(const void* g, void* l) {
  __builtin_amdgcn_global_load_lds(
      (const __attribute__((address_space(1))) void*)g,
      (__attribute__((address_space(3))) void*)l, 16, 0, 0);
}

// ---------------- fp32 -> bf16 cast ----------------
__global__ __launch_bounds__(256) void cvt_f32_bf16(const float* __restrict__ in,
                                                    unsigned short* __restrict__ out,
                                                    int n4) {
  int i = blockIdx.x * 256 + threadIdx.x;
  if (i < n4) {
    float4 v = ((const float4*)in)[i];
    ushort4 o;
    o.x = f2bf(v.x); o.y = f2bf(v.y); o.z = f2bf(v.z); o.w = f2bf(v.w);
    ((ushort4*)out)[i] = o;
  }
}

// ---------------- shared GEMM pieces ----------------
// Stage 128(rows) x 64(cols) bf16 tile into LDS, linear [128][64] (128B rows),
// read-side XOR swizzle compensated in the global SOURCE address (m201 pattern).
// Swizzle: byte_off ^= ((row&7)<<4).
__device__ __forceinline__ void stage128x64(const unsigned short* __restrict__ g,
                                            long ldb, long row0, long k0b,
                                            unsigned short* lds, int w, int l) {
  const char* gp = (const char*)g + (row0 + (long)(w * 8 + (l >> 3))) * ldb + k0b +
                   (long)(((l & 7) ^ (l >> 3)) << 4);
  char* lp = (char*)lds + w * 1024;
#pragma unroll
  for (int i = 0; i < 4; ++i) {
    gload_lds16(gp + (long)i * 32 * ldb, lp + i * 4096);
  }
}

__device__ __forceinline__ bf16x8 frag_ld(const unsigned short* lds, int row, int cb) {
  return *(const bf16x8*)((const char*)lds + row * 128 + (cb ^ ((row & 7) << 4)));
}

// 128x128 output tile, K=1024, A and B^T both row-major with 2048-byte rows.
__device__ __forceinline__ void gemm_loop(const unsigned short* __restrict__ A,
                                          const unsigned short* __restrict__ Bm,
                                          long m0, long n0,
                                          unsigned short* aT, unsigned short* bT,
                                          int w, int l, f32x4 acc[4][4]) {
  const int wr = (w >> 1) * 64, wc = (w & 1) * 64;
  const int l15 = l & 15;
  for (int ks = 0; ks < 1024; ks += 64) {
    __syncthreads();
    stage128x64(A, 2048, m0, (long)ks * 2, aT, w, l);
    stage128x64(Bm, 2048, n0, (long)ks * 2, bT, w, l);
    __syncthreads();
#pragma unroll
    for (int kk = 0; kk < 2; ++kk) {
      const int cb = kk * 64 + (l >> 4) * 16;
      bf16x8 af[4], bfr[4];
#pragma unroll
      for (int t = 0; t < 4; ++t) af[t] = frag_ld(aT, wr + t * 16 + l15, cb);
#pragma unroll
      for (int t = 0; t < 4; ++t) bfr[t] = frag_ld(bT, wc + t * 16 + l15, cb);
#pragma unroll
      for (int mt = 0; mt < 4; ++mt)
#pragma unroll
        for (int nt = 0; nt < 4; ++nt)
          acc[mt][nt] = __builtin_amdgcn_mfma_f32_16x16x32_bf16(af[mt], bfr[nt],
                                                                acc[mt][nt], 0, 0, 0);
    }
  }
}

// ---------------- QKV projection + clamp + layout scatter ----------------
// C[4096][3072] = x @ qkv_w^T + b;  cols: t=n>>10 (0:q 1:k 2:v), h=(n>>6)&15, d=n&63
// q,k -> [B*H][S][64] bf16 ; v -> transposed [B*H][64][S] bf16
__global__ __launch_bounds__(256) void qkv_gemm(
    const unsigned short* __restrict__ xb, const unsigned short* __restrict__ wb,
    const float* __restrict__ bias,
    const float* __restrict__ akmin, const float* __restrict__ akmax,
    const float* __restrict__ avmin, const float* __restrict__ avmax,
    unsigned short* __restrict__ qo, unsigned short* __restrict__ ko,
    unsigned short* __restrict__ vto) {
  __shared__ __align__(16) unsigned short aT[128 * 64];
  __shared__ __align__(16) unsigned short bT[128 * 64];
  const int tid = threadIdx.x, l = tid & 63, w = tid >> 6;
  const long m0 = (long)blockIdx.y * 128, n0 = (long)blockIdx.x * 128;
  f32x4 acc[4][4] = {};
  gemm_loop(xb, wb, m0, n0, aT, bT, w, l, acc);

  const int wr = (w >> 1) * 64, wc = (w & 1) * 64;
  const int l15 = l & 15, lg = l >> 4;
  const int t = (int)(n0 >> 10);  // uniform per block (n0 multiple of 128)
#pragma unroll
  for (int nt = 0; nt < 4; ++nt) {
    const int n = (int)n0 + wc + nt * 16 + l15;
    const float bv = bias[n];
    const int h = (n >> 6) & 15, d = n & 63;
#pragma unroll
    for (int mt = 0; mt < 4; ++mt) {
#pragma unroll
      for (int j = 0; j < 4; ++j) {
        const long m = m0 + wr + mt * 16 + lg * 4 + j;
        const int b = (int)(m >> 11), s = (int)(m & 2047);
        const int bh = b * 16 + h;
        float v = acc[mt][nt][j] + bv;
        if (t == 0) {
          qo[((long)bh * 2048 + s) * 64 + d] = f2bf(v);
        } else if (t == 1) {
          const int ai = bh * 64 + d;
          float lo = fmaxf(v - EPSG, akmin[ai]);
          float hi = fminf(v + EPSG, akmax[ai]);
          lo = fminf(lo, hi);
          v = fmaxf(lo, fminf(v, hi));
          ko[((long)bh * 2048 + s) * 64 + d] = f2bf(v);
        } else {
          const int ai = bh * 64 + d;
          float lo = fmaxf(v - EPSG, avmin[ai]);
          float hi = fminf(v + EPSG, avmax[ai]);
          lo = fminf(lo, hi);
          v = fmaxf(lo, fminf(v, hi));
          vto[((long)bh * 64 + d) * 2048 + s] = f2bf(v);
        }
      }
    }
  }
}

// ---------------- flash attention ----------------
// grid (32 qtiles, 32 bh), 4 waves; wave owns 16 q-rows; KBLK=64; dk=64.
__global__ __launch_bounds__(256) void attn_fwd(
    const unsigned short* __restrict__ q, const unsigned short* __restrict__ k,
    const unsigned short* __restrict__ vt, unsigned short* __restrict__ o) {
  __shared__ __align__(16) unsigned short p_lds[4 * 16 * 64];  // per-wave 2KB slot
  const int tid = threadIdx.x, l = tid & 63, w = tid >> 6;
  const int l15 = l & 15, lg = l >> 4;
  const int qt = blockIdx.x, bh = blockIdx.y;

  const unsigned short* qbase = q + ((long)bh * 2048 + qt * 64 + w * 16) * 64;
  bf16x8 qf[2];
#pragma unroll
  for (int kk = 0; kk < 2; ++kk)
    qf[kk] = *(const bf16x8*)(qbase + (long)l15 * 64 + kk * 32 + lg * 8);

  float m_run[4], l_run[4];
  f32x4 oacc[4] = {};
#pragma unroll
  for (int j = 0; j < 4; ++j) { m_run[j] = -3.0e38f; l_run[j] = 0.f; }

  unsigned short* pw = p_lds + w * 16 * 64;
  const unsigned short* kb0 = k + (long)bh * 2048 * 64;
  const unsigned short* vb0 = vt + (long)bh * 64 * 2048;

  for (int kt = 0; kt < 32; ++kt) {
    // S = q @ k^T (per-wave 16x64 tile)
    f32x4 sc[4] = {};
#pragma unroll
    for (int kk = 0; kk < 2; ++kk) {
#pragma unroll
      for (int ct = 0; ct < 4; ++ct) {
        bf16x8 kf = *(const bf16x8*)(kb0 + ((long)(kt * 64 + ct * 16 + l15)) * 64 +
                                     kk * 32 + lg * 8);
        sc[ct] = __builtin_amdgcn_mfma_f32_16x16x32_bf16(qf[kk], kf, sc[ct], 0, 0, 0);
      }
    }
    // online softmax; rows handled by this lane: lg*4 + j
#pragma unroll
    for (int j = 0; j < 4; ++j) {
      float s0 = sc[0][j] * 0.125f, s1 = sc[1][j] * 0.125f;
      float s2 = sc[2][j] * 0.125f, s3 = sc[3][j] * 0.125f;
      float mx = fmaxf(fmaxf(s0, s1), fmaxf(s2, s3));
#pragma unroll
      for (int msk = 1; msk < 16; msk <<= 1) mx = fmaxf(mx, __shfl_xor(mx, msk, 64));
      const float mn = fmaxf(m_run[j], mx);
      const float alpha = __expf(m_run[j] - mn);
      const float p0 = __expf(s0 - mn), p1 = __expf(s1 - mn);
      const float p2 = __expf(s2 - mn), p3 = __expf(s3 - mn);
      float rs = p0 + p1 + p2 + p3;
#pragma unroll
      for (int msk = 1; msk < 16; msk <<= 1) rs += __shfl_xor(rs, msk, 64);
      l_run[j] = l_run[j] * alpha + rs;
      m_run[j] = mn;
#pragma unroll
      for (int nt = 0; nt < 4; ++nt) oacc[nt][j] *= alpha;
      // P -> swizzled per-wave LDS (row = lg*4+j, col = ct*16+l15)
      const int lr = lg * 4 + j;
      const int swz = (lr & 7) << 4;
      char* base = (char*)pw + lr * 128;
      *(unsigned short*)(base + ((0 * 32 + l15 * 2) ^ swz)) = f2bf(p0);
      *(unsigned short*)(base + ((1 * 32 + l15 * 2) ^ swz)) = f2bf(p1);
      *(unsigned short*)(base + ((2 * 32 + l15 * 2) ^ swz)) = f2bf(p2);
      *(unsigned short*)(base + ((3 * 32 + l15 * 2) ^ swz)) = f2bf(p3);
    }
    // O += P @ V   (P from LDS as A-frag; V^T direct from global as B-frag)
#pragma unroll
    for (int kk = 0; kk < 2; ++kk) {
      const int row = l15;
      const int cb = kk * 64 + lg * 16;
      bf16x8 pf = *(const bf16x8*)((const char*)pw + row * 128 + (cb ^ ((row & 7) << 4)));
#pragma unroll
      for (int nt = 0; nt < 4; ++nt) {
        bf16x8 vf = *(const bf16x8*)(vb0 + ((long)(nt * 16 + l15)) * 2048 + kt * 64 +
                                     kk * 32 + lg * 8);
        oacc[nt] = __builtin_amdgcn_mfma_f32_16x16x32_bf16(pf, vf, oacc[nt], 0, 0, 0);
      }
    }
  }
  // epilogue: o[b][s][h*64+d] bf16
  const int b = bh >> 4, h = bh & 15;
#pragma unroll
  for (int j = 0; j < 4; ++j) {
    const float inv = 1.f / l_run[j];
    const long s = (long)qt * 64 + w * 16 + lg * 4 + j;
    unsigned short* orow = o + ((long)b * 2048 + s) * 1024 + h * 64;
#pragma unroll
    for (int nt = 0; nt < 4; ++nt) orow[nt * 16 + l15] = f2bf(oacc[nt][j] * inv);
  }
}

// ---------------- output projection ----------------
__global__ __launch_bounds__(256) void out_gemm(const unsigned short* __restrict__ ab,
                                                const unsigned short* __restrict__ wb,
                                                const float* __restrict__ bias,
                                                float* __restrict__ out) {
  __shared__ __align__(16) unsigned short aT[128 * 64];
  __shared__ __align__(16) unsigned short bT[128 * 64];
  const int tid = threadIdx.x, l = tid & 63, w = tid >> 6;
  const long m0 = (long)blockIdx.y * 128, n0 = (long)blockIdx.x * 128;
  f32x4 acc[4][4] = {};
  gemm_loop(ab, wb, m0, n0, aT, bT, w, l, acc);

  const int wr = (w >> 1) * 64, wc = (w & 1) * 64;
  const int l15 = l & 15, lg = l >> 4;
#pragma unroll
  for (int nt = 0; nt < 4; ++nt) {
    const int n = (int)n0 + wc + nt * 16 + l15;
    const float bv = bias[n];
#pragma unroll
    for (int mt = 0; mt < 4; ++mt) {
#pragma unroll
      for (int j = 0; j < 4; ++j) {
        const long m = m0 + wr + mt * 16 + lg * 4 + j;
        out[m * 1024 + n] = acc[mt][nt][j] + bv;
      }
    }
  }
}

extern "C" void kernel_launch(void* const* d_in, const int* in_sizes, int n_in,
                              void* d_out, int out_size, void* d_ws, size_t ws_size,
                              hipStream_t stream) {
  const float* x = (const float*)d_in[0];
  const float* qkv_w = (const float*)d_in[1];
  const float* qkv_b = (const float*)d_in[2];
  const float* out_w = (const float*)d_in[3];
  const float* out_b = (const float*)d_in[4];
  const float* akmin = (const float*)d_in[5];
  const float* akmax = (const float*)d_in[6];
  const float* avmin = (const float*)d_in[7];
  const float* avmax = (const float*)d_in[8];

  char* ws = (char*)d_ws;
  const long MB = 1024 * 1024;
  unsigned short* xb  = (unsigned short*)(ws + 0 * MB);    // 8 MB  [4096][1024]
  unsigned short* wqb = (unsigned short*)(ws + 8 * MB);    // 6 MB  [3072][1024]
  unsigned short* wob = (unsigned short*)(ws + 14 * MB);   // 2 MB  [1024][1024]
  unsigned short* qb  = (unsigned short*)(ws + 16 * MB);   // 8 MB  [32][2048][64]
  unsigned short* kb  = (unsigned short*)(ws + 24 * MB);   // 8 MB  [32][2048][64]
  unsigned short* vtb = (unsigned short*)(ws + 32 * MB);   // 8 MB  [32][64][2048]
  unsigned short* ob  = (unsigned short*)(ws + 40 * MB);   // 8 MB  [4096][1024]

  cvt_f32_bf16<<<4096, 256, 0, stream>>>(x, xb, 4096 * 1024 / 4);
  cvt_f32_bf16<<<3072, 256, 0, stream>>>(qkv_w, wqb, 3072 * 1024 / 4);
  cvt_f32_bf16<<<1024, 256, 0, stream>>>(out_w, wob, 1024 * 1024 / 4);
  qkv_gemm<<<dim3(24, 32), 256, 0, stream>>>(xb, wqb, qkv_b, akmin, akmax, avmin,
                                             avmax, qb, kb, vtb);
  attn_fwd<<<dim3(32, 32), 256, 0, stream>>>(qb, kb, vtb, ob);
  out_gemm<<<dim3(8, 32), 256, 0, stream>>>(ob, wob, out_b, (float*)d_out);
}

// Round 3
// 156.835 us; speedup vs baseline: 2.1502x; 2.1502x over previous
//
#include <hip/hip_runtime.h>

// Range-aware attention, bf16 MFMA pipeline.
// B=2, S=2048, D=1024, H=16, dk=64. EPS=0.1.

typedef __bf16 bf16x8 __attribute__((ext_vector_type(8)));
typedef float f32x4 __attribute__((ext_vector_type(4)));

#define EPSG 0.1f

__device__ __forceinline__ unsigned short f2bf(float f) {
  unsigned int u = __float_as_uint(f);
  u += 0x7FFFu + ((u >> 16) & 1u);   // RNE
  return (unsigned short)(u >> 16);
}

__device__ __forceinline__ void gload_lds16(const void* g, void* l) {
  __builtin_amdgcn_global_load_lds(
      (const __attribute__((address_space(1))) void*)g,
      (__attribute__((address_space(3))) void*)l, 16, 0, 0);
}

// ---------------- fp32 -> bf16 cast ----------------
__global__ __launch_bounds__(256) void cvt_f32_bf16(const float* __restrict__ in,
                                                    unsigned short* __restrict__ out,
                                                    int n4) {
  int i = blockIdx.x * 256 + threadIdx.x;
  if (i < n4) {
    float4 v = ((const float4*)in)[i];
    ushort4 o;
    o.x = f2bf(v.x); o.y = f2bf(v.y); o.z = f2bf(v.z); o.w = f2bf(v.w);
    ((ushort4*)out)[i] = o;
  }
}

// ---------------- shared GEMM pieces ----------------
__device__ __forceinline__ void stage128x64(const unsigned short* __restrict__ g,
                                            long ldb, long row0, long k0b,
                                            unsigned short* lds, int w, int l) {
  const char* gp = (const char*)g + (row0 + (long)(w * 8 + (l >> 3))) * ldb + k0b +
                   (long)(((l & 7) ^ (l >> 3)) << 4);
  char* lp = (char*)lds + w * 1024;
#pragma unroll
  for (int i = 0; i < 4; ++i) {
    gload_lds16(gp + (long)i * 32 * ldb, lp + i * 4096);
  }
}

__device__ __forceinline__ bf16x8 frag_ld(const unsigned short* lds, int row, int cb) {
  return *(const bf16x8*)((const char*)lds + row * 128 + (cb ^ ((row & 7) << 4)));
}

// 128x128 output tile, K=1024, A and B^T both row-major with 2048-byte rows.
__device__ __forceinline__ void gemm_loop(const unsigned short* __restrict__ A,
                                          const unsigned short* __restrict__ Bm,
                                          long m0, long n0,
                                          unsigned short* aT, unsigned short* bT,
                                          int w, int l, f32x4 acc[4][4]) {
  const int wr = (w >> 1) * 64, wc = (w & 1) * 64;
  const int l15 = l & 15;
  for (int ks = 0; ks < 1024; ks += 64) {
    __syncthreads();
    stage128x64(A, 2048, m0, (long)ks * 2, aT, w, l);
    stage128x64(Bm, 2048, n0, (long)ks * 2, bT, w, l);
    __syncthreads();
#pragma unroll
    for (int kk = 0; kk < 2; ++kk) {
      const int cb = kk * 64 + (l >> 4) * 16;
      bf16x8 af[4], bfr[4];
#pragma unroll
      for (int t = 0; t < 4; ++t) af[t] = frag_ld(aT, wr + t * 16 + l15, cb);
#pragma unroll
      for (int t = 0; t < 4; ++t) bfr[t] = frag_ld(bT, wc + t * 16 + l15, cb);
#pragma unroll
      for (int mt = 0; mt < 4; ++mt)
#pragma unroll
        for (int nt = 0; nt < 4; ++nt)
          acc[mt][nt] = __builtin_amdgcn_mfma_f32_16x16x32_bf16(af[mt], bfr[nt],
                                                                acc[mt][nt], 0, 0, 0);
    }
  }
}

// ---------------- QKV projection + clamp + layout scatter ----------------
// q stored PRE-SCALED by 1/8 (exact).  q,k -> [B*H][S][64]; v -> [B*H][64][S].
__global__ __launch_bounds__(256) void qkv_gemm(
    const unsigned short* __restrict__ xb, const unsigned short* __restrict__ wb,
    const float* __restrict__ bias,
    const float* __restrict__ akmin, const float* __restrict__ akmax,
    const float* __restrict__ avmin, const float* __restrict__ avmax,
    unsigned short* __restrict__ qo, unsigned short* __restrict__ ko,
    unsigned short* __restrict__ vto) {
  __shared__ __align__(16) unsigned short aT[128 * 64];
  __shared__ __align__(16) unsigned short bT[128 * 64];
  const int tid = threadIdx.x, l = tid & 63, w = tid >> 6;
  const long m0 = (long)blockIdx.y * 128, n0 = (long)blockIdx.x * 128;
  f32x4 acc[4][4] = {};
  gemm_loop(xb, wb, m0, n0, aT, bT, w, l, acc);

  const int wr = (w >> 1) * 64, wc = (w & 1) * 64;
  const int l15 = l & 15, lg = l >> 4;
  const int t = (int)(n0 >> 10);  // uniform per block
#pragma unroll
  for (int nt = 0; nt < 4; ++nt) {
    const int n = (int)n0 + wc + nt * 16 + l15;
    const float bv = bias[n];
    const int h = (n >> 6) & 15, d = n & 63;
#pragma unroll
    for (int mt = 0; mt < 4; ++mt) {
      const long s0 = m0 + wr + mt * 16 + lg * 4;
      const int b = (int)(s0 >> 11), s_lo = (int)(s0 & 2047);
      const int bh = b * 16 + h;
      if (t == 0) {
#pragma unroll
        for (int j = 0; j < 4; ++j) {
          float v = (acc[mt][nt][j] + bv) * 0.125f;  // exact pre-scale by 1/sqrt(dk)
          qo[((long)bh * 2048 + s_lo + j) * 64 + d] = f2bf(v);
        }
      } else if (t == 1) {
        const int ai = bh * 64 + d;
        const float amn = akmin[ai], amx = akmax[ai];
#pragma unroll
        for (int j = 0; j < 4; ++j) {
          float v = acc[mt][nt][j] + bv;
          float lo = fmaxf(v - EPSG, amn);
          float hi = fminf(v + EPSG, amx);
          lo = fminf(lo, hi);
          v = fmaxf(lo, fminf(v, hi));
          ko[((long)bh * 2048 + s_lo + j) * 64 + d] = f2bf(v);
        }
      } else {
        const int ai = bh * 64 + d;
        const float amn = avmin[ai], amx = avmax[ai];
        ushort4 pk;
        unsigned short* pp = (unsigned short*)&pk;
#pragma unroll
        for (int j = 0; j < 4; ++j) {
          float v = acc[mt][nt][j] + bv;
          float lo = fmaxf(v - EPSG, amn);
          float hi = fminf(v + EPSG, amx);
          lo = fminf(lo, hi);
          v = fmaxf(lo, fminf(v, hi));
          pp[j] = f2bf(v);
        }
        // FIX (R2 bug): use s_lo (batch-local seq index), NOT s0 — bh already
        // encodes the batch; using s0 wrote batch 1 into row d+1.
        *(ushort4*)(vto + ((long)bh * 64 + d) * 2048 + s_lo) = pk;
      }
    }
  }
}

// ---------------- flash attention ----------------
// grid (32 qtiles, 32 bh), 4 waves; wave owns 16 q-rows; KVBLK=64.
// K/V^T tiles cooperatively staged to LDS (double-buffered, swizzled).
// Softmax: defer-max (THR=8) + per-lane deferred sum (reduced once at end).
__global__ __launch_bounds__(256) void attn_fwd(
    const unsigned short* __restrict__ q, const unsigned short* __restrict__ k,
    const unsigned short* __restrict__ vt, unsigned short* __restrict__ o) {
  __shared__ __align__(16) unsigned short kT[2][64 * 64];
  __shared__ __align__(16) unsigned short vT[2][64 * 64];
  __shared__ __align__(16) unsigned short p_lds[4 * 16 * 64];
  const int tid = threadIdx.x, l = tid & 63, w = tid >> 6;
  const int l15 = l & 15, lg = l >> 4;
  const int qt = blockIdx.x, bh = blockIdx.y;

  const char* kbC = (const char*)(k + (long)bh * 2048 * 64);
  const char* vbC = (const char*)(vt + (long)bh * 64 * 2048);

  // Q fragments (already scaled by 1/8)
  const unsigned short* qbase = q + ((long)bh * 2048 + qt * 64 + w * 16) * 64;
  bf16x8 qf[2];
#pragma unroll
  for (int kk = 0; kk < 2; ++kk)
    qf[kk] = *(const bf16x8*)(qbase + (long)l15 * 64 + kk * 32 + lg * 8);

  float m_run[4], l_part[4];
  f32x4 oacc[4] = {};
#pragma unroll
  for (int j = 0; j < 4; ++j) { m_run[j] = -1e30f; l_part[j] = 0.f; }

  unsigned short* pw = p_lds + w * 1024;
  const int srow = l >> 3;                    // 0..7
  const int schk = ((l & 7) ^ srow) << 4;     // pre-swizzled source chunk

#define STAGE_KV(kt_, buf_)                                                      \
  do {                                                                           \
    const char* sK = kbC + (long)((kt_)*64 + w * 8 + srow) * 128 + schk;         \
    char* dK = (char*)kT[buf_] + w * 1024;                                       \
    gload_lds16(sK, dK);                                                         \
    gload_lds16(sK + 32 * 128, dK + 4096);                                       \
    const char* sV = vbC + (long)(w * 8 + srow) * 4096 + (long)(kt_)*128 + schk; \
    char* dV = (char*)vT[buf_] + w * 1024;                                       \
    gload_lds16(sV, dV);                                                         \
    gload_lds16(sV + 32 * 4096, dV + 4096);                                      \
  } while (0)

  STAGE_KV(0, 0);
  asm volatile("s_waitcnt vmcnt(0)" ::: "memory");
  __syncthreads();

  for (int kt = 0; kt < 32; ++kt) {
    const int cur = kt & 1;
    if (kt < 31) STAGE_KV(kt + 1, cur ^ 1);
    const unsigned short* kTc = kT[cur];
    const unsigned short* vTc = vT[cur];

    // S = q @ k^T (per-wave 16x64 tile), scores already scaled
    f32x4 sc[4] = {};
    __builtin_amdgcn_s_setprio(1);
#pragma unroll
    for (int kk = 0; kk < 2; ++kk) {
      const int cb = kk * 64 + lg * 16;
#pragma unroll
      for (int ct = 0; ct < 4; ++ct) {
        const int row = ct * 16 + l15;
        bf16x8 kf = *(const bf16x8*)((const char*)kTc + row * 128 +
                                     (cb ^ ((row & 7) << 4)));
        sc[ct] = __builtin_amdgcn_mfma_f32_16x16x32_bf16(qf[kk], kf, sc[ct], 0, 0, 0);
      }
    }
    __builtin_amdgcn_s_setprio(0);

    // in-lane per-row tile max
    float pm[4];
#pragma unroll
    for (int j = 0; j < 4; ++j)
      pm[j] = fmaxf(fmaxf(sc[0][j], sc[1][j]), fmaxf(sc[2][j], sc[3][j]));
    int cond = (pm[0] <= m_run[0] + 8.f) & (pm[1] <= m_run[1] + 8.f) &
               (pm[2] <= m_run[2] + 8.f) & (pm[3] <= m_run[3] + 8.f);
    if (!__all(cond)) {
      // slow path: full max reduce + rescale (rare: kt==0 and outliers)
#pragma unroll
      for (int j = 0; j < 4; ++j) {
        float mx = pm[j];
#pragma unroll
        for (int msk = 1; msk < 16; msk <<= 1) mx = fmaxf(mx, __shfl_xor(mx, msk, 64));
        mx = fmaxf(mx, m_run[j]);
        const float alpha = __expf(m_run[j] - mx);
        m_run[j] = mx;
        l_part[j] *= alpha;
#pragma unroll
        for (int nt = 0; nt < 4; ++nt) oacc[nt][j] *= alpha;
      }
    }
    // P = exp(S - m); per-lane partial sums only (reduced at the end)
#pragma unroll
    for (int j = 0; j < 4; ++j) {
      const float p0 = __expf(sc[0][j] - m_run[j]);
      const float p1 = __expf(sc[1][j] - m_run[j]);
      const float p2 = __expf(sc[2][j] - m_run[j]);
      const float p3 = __expf(sc[3][j] - m_run[j]);
      l_part[j] += (p0 + p1) + (p2 + p3);
      const int lr = lg * 4 + j;
      const int swz = (lr & 7) << 4;
      char* base = (char*)pw + lr * 128;
      *(unsigned short*)(base + ((0 * 32 + l15 * 2) ^ swz)) = f2bf(p0);
      *(unsigned short*)(base + ((1 * 32 + l15 * 2) ^ swz)) = f2bf(p1);
      *(unsigned short*)(base + ((2 * 32 + l15 * 2) ^ swz)) = f2bf(p2);
      *(unsigned short*)(base + ((3 * 32 + l15 * 2) ^ swz)) = f2bf(p3);
    }
    // O += P @ V
    __builtin_amdgcn_s_setprio(1);
#pragma unroll
    for (int kk = 0; kk < 2; ++kk) {
      const int cb = kk * 64 + lg * 16;
      bf16x8 pf = *(const bf16x8*)((const char*)pw + l15 * 128 +
                                   (cb ^ ((l15 & 7) << 4)));
#pragma unroll
      for (int nt = 0; nt < 4; ++nt) {
        const int row = nt * 16 + l15;
        bf16x8 vf = *(const bf16x8*)((const char*)vTc + row * 128 +
                                     (cb ^ ((row & 7) << 4)));
        oacc[nt] = __builtin_amdgcn_mfma_f32_16x16x32_bf16(pf, vf, oacc[nt], 0, 0, 0);
      }
    }
    __builtin_amdgcn_s_setprio(0);
    asm volatile("s_waitcnt vmcnt(0)" ::: "memory");
    __syncthreads();
  }

  // final cross-lane sum reduce (once)
  float l_run[4];
#pragma unroll
  for (int j = 0; j < 4; ++j) {
    float rs = l_part[j];
#pragma unroll
    for (int msk = 1; msk < 16; msk <<= 1) rs += __shfl_xor(rs, msk, 64);
    l_run[j] = rs;
  }
  const int b = bh >> 4, h = bh & 15;
#pragma unroll
  for (int j = 0; j < 4; ++j) {
    const float inv = 1.f / l_run[j];
    const long s = (long)qt * 64 + w * 16 + lg * 4 + j;
    unsigned short* orow = o + ((long)b * 2048 + s) * 1024 + h * 64;
#pragma unroll
    for (int nt = 0; nt < 4; ++nt) orow[nt * 16 + l15] = f2bf(oacc[nt][j] * inv);
  }
#undef STAGE_KV
}

// ---------------- output projection ----------------
__global__ __launch_bounds__(256) void out_gemm(const unsigned short* __restrict__ ab,
                                                const unsigned short* __restrict__ wb,
                                                const float* __restrict__ bias,
                                                float* __restrict__ out) {
  __shared__ __align__(16) unsigned short aT[128 * 64];
  __shared__ __align__(16) unsigned short bT[128 * 64];
  const int tid = threadIdx.x, l = tid & 63, w = tid >> 6;
  const long m0 = (long)blockIdx.y * 128, n0 = (long)blockIdx.x * 128;
  f32x4 acc[4][4] = {};
  gemm_loop(ab, wb, m0, n0, aT, bT, w, l, acc);

  const int wr = (w >> 1) * 64, wc = (w & 1) * 64;
  const int l15 = l & 15, lg = l >> 4;
#pragma unroll
  for (int nt = 0; nt < 4; ++nt) {
    const int n = (int)n0 + wc + nt * 16 + l15;
    const float bv = bias[n];
#pragma unroll
    for (int mt = 0; mt < 4; ++mt) {
#pragma unroll
      for (int j = 0; j < 4; ++j) {
        const long m = m0 + wr + mt * 16 + lg * 4 + j;
        out[m * 1024 + n] = acc[mt][nt][j] + bv;
      }
    }
  }
}

extern "C" void kernel_launch(void* const* d_in, const int* in_sizes, int n_in,
                              void* d_out, int out_size, void* d_ws, size_t ws_size,
                              hipStream_t stream) {
  const float* x = (const float*)d_in[0];
  const float* qkv_w = (const float*)d_in[1];
  const float* qkv_b = (const float*)d_in[2];
  const float* out_w = (const float*)d_in[3];
  const float* out_b = (const float*)d_in[4];
  const float* akmin = (const float*)d_in[5];
  const float* akmax = (const float*)d_in[6];
  const float* avmin = (const float*)d_in[7];
  const float* avmax = (const float*)d_in[8];

  char* ws = (char*)d_ws;
  const long MB = 1024 * 1024;
  unsigned short* xb  = (unsigned short*)(ws + 0 * MB);    // 8 MB  [4096][1024]
  unsigned short* wqb = (unsigned short*)(ws + 8 * MB);    // 6 MB  [3072][1024]
  unsigned short* wob = (unsigned short*)(ws + 14 * MB);   // 2 MB  [1024][1024]
  unsigned short* qb  = (unsigned short*)(ws + 16 * MB);   // 8 MB  [32][2048][64] (q/8)
  unsigned short* kb  = (unsigned short*)(ws + 24 * MB);   // 8 MB  [32][2048][64]
  unsigned short* vtb = (unsigned short*)(ws + 32 * MB);   // 8 MB  [32][64][2048]
  unsigned short* ob  = (unsigned short*)(ws + 40 * MB);   // 8 MB  [4096][1024]

  cvt_f32_bf16<<<4096, 256, 0, stream>>>(x, xb, 4096 * 1024 / 4);
  cvt_f32_bf16<<<3072, 256, 0, stream>>>(qkv_w, wqb, 3072 * 1024 / 4);
  cvt_f32_bf16<<<1024, 256, 0, stream>>>(out_w, wob, 1024 * 1024 / 4);
  qkv_gemm<<<dim3(24, 32), 256, 0, stream>>>(xb, wqb, qkv_b, akmin, akmax, avmin,
                                             avmax, qb, kb, vtb);
  attn_fwd<<<dim3(32, 32), 256, 0, stream>>>(qb, kb, vtb, ob);
  out_gemm<<<dim3(8, 32), 256, 0, stream>>>(ob, wob, out_b, (float*)d_out);
}